// Round 15
// baseline (145.592 us; speedup 1.0000x reference)
//
#include <hip/hip_runtime.h>

typedef __bf16 bf16_t;
typedef __bf16 bf16x8 __attribute__((ext_vector_type(8)));
typedef __bf16 bf16x4 __attribute__((ext_vector_type(4)));
typedef _Float16 f16x2 __attribute__((ext_vector_type(2)));
typedef _Float16 f16x4 __attribute__((ext_vector_type(4)));
typedef _Float16 f16x8 __attribute__((ext_vector_type(8)));
typedef float f32x4 __attribute__((ext_vector_type(4)));

#define B_   2
#define T_   2048
#define C_   768
#define NH_  12
#define HS_  64
#define N3_  2304
#define M_   4096
#define QSCALE 0.18033688011112042f   // 0.125 * log2(e), folded into Q at GEMM epilogue

__device__ __forceinline__ bf16_t f2bf(float f) {
  unsigned u = __builtin_bit_cast(unsigned, f);
  u += 0x7fffu + ((u >> 16) & 1u);           // round-to-nearest-even
  unsigned short s = (unsigned short)(u >> 16);
  return __builtin_bit_cast(bf16_t, s);
}

// ---------------- fused casts: x fp32->bf16, w fp32 [K][N] -> wt bf16 [N][K] ----------------
// Exact R23 version (best-measured total 141.1us).
__global__ __launch_bounds__(256) void cvt_xw_kernel(const float* __restrict__ x,
                                                     const float* __restrict__ w,
                                                     bf16_t* __restrict__ xb,
                                                     bf16_t* __restrict__ wt) {
  __shared__ float tile[32][33];
  int bx = blockIdx.x;
  if (bx < 3072) {
    int i = (bx * 256 + threadIdx.x) * 4;
    float4 v = *reinterpret_cast<const float4*>(x + i);
    xb[i + 0] = f2bf(v.x);
    xb[i + 1] = f2bf(v.y);
    xb[i + 2] = f2bf(v.z);
    xb[i + 3] = f2bf(v.w);
  } else {
    int b = bx - 3072;                 // 0..1727
    int k0 = (b % 24) * 32, n0 = (b / 24) * 32;
    int tx = threadIdx.x & 31, ty = threadIdx.x >> 5;   // 32 x 8
#pragma unroll
    for (int i = 0; i < 4; i++)
      tile[ty + i * 8][tx] = w[(size_t)(k0 + ty + i * 8) * N3_ + n0 + tx];
    __syncthreads();
#pragma unroll
    for (int i = 0; i < 4; i++)
      wt[(size_t)(n0 + ty + i * 8) * C_ + k0 + tx] = f2bf(tile[tx][ty + i * 8]);
  }
}

// ---------------- qkv GEMM: R15 pipeline + 2D-region XCD pinning (R23) ---------------------
// R23: linear-grid L2 thrash (FETCH 42.4MB = 4.2x) fixed by region pinning: xcd = id&7 ->
// (xcd&1) col-half x (xcd>>1) row-quarter; per-XCD footprint 3.3MB < 4MB L2.
// R28 change: V epilogue writes va in the ATTN-FRAGMENT-DIRECT layout -- f16 index
// bh*131072 + kt*4096 + ni*1024 + p*512 + lane*8 + e, derived by composing the old linear
// layout with R21's staging permutation (bytes: f(ni,p,L) <-> g = ni*2048 + (L>>1)*64 +
// (L&1)*32 + p*16). Same f16x4 store width, same values -> attn can read V fragments
// directly from global, 1024B contiguous per (ni,p) wave read.
__global__ __launch_bounds__(256) void gemm_qkv(const bf16_t* __restrict__ xb,
                                                const bf16_t* __restrict__ wt,
                                                const float* __restrict__ bias,
                                                bf16_t* __restrict__ qout,
                                                bf16_t* __restrict__ kout,
                                                _Float16* __restrict__ va) {
  __shared__ bf16_t As[2][64 * 32];    // [buf][m][k] panel, flat, no pad (64B rows)
  __shared__ bf16_t Bs[2][128 * 32];
  const int tid = threadIdx.x;
  const int lane = tid & 63, wave = tid >> 6;
  const int wm = wave >> 1, wn = wave & 1;   // 2(M) x 2(N) waves; wave tile 32x64
  const int quad = lane >> 4, l15 = lane & 15;

  // 2D-region XCD decode: 8 regions of 9 cols x 16 rows (144 blocks each)
  const int id = (int)blockIdx.x;           // 0..1151
  const int xcd = id & 7, r = id >> 3;      // r: 0..143
  const int cx = r % 9, ry = r / 9;         // col-fastest within region (A-panel reuse)
  const int bx = (xcd & 1) * 9 + cx;        // 0..17
  const int by = (xcd >> 1) * 16 + ry;      // 0..63
  const int row0 = by * 64;
  const int col0 = bx * 128;
  const bool isqk = (col0 < 1536);

  f32x4 acc[2][4];
#pragma unroll
  for (int mi = 0; mi < 2; mi++)
#pragma unroll
    for (int ni = 0; ni < 4; ni++) acc[mi][ni] = f32x4{0.f, 0.f, 0.f, 0.f};

  const int r0 = tid >> 2, q0 = tid & 3;
  const int r1 = (256 + tid) >> 2, q1 = (256 + tid) & 3;
  const bf16_t* gA0 = xb + (size_t)(row0 + r0) * C_ + q0 * 8;
  const bf16_t* gB0 = wt + (size_t)(col0 + r0) * C_ + q0 * 8;
  const bf16_t* gB1 = wt + (size_t)(col0 + r1) * C_ + q1 * 8;
  const int ldsOff0 = (wave * 64) * 16;          // chunk block c=0
  const int ldsOff1 = (256 + wave * 64) * 16;    // chunk block c=1

  auto STAGE = [&](int buf, int k0) {
    __builtin_amdgcn_global_load_lds((const __attribute__((address_space(1))) void*)(gA0 + k0),
                                     (__attribute__((address_space(3))) void*)((char*)As[buf] + ldsOff0), 16, 0, 0);
    __builtin_amdgcn_global_load_lds((const __attribute__((address_space(1))) void*)(gB0 + k0),
                                     (__attribute__((address_space(3))) void*)((char*)Bs[buf] + ldsOff0), 16, 0, 0);
    __builtin_amdgcn_global_load_lds((const __attribute__((address_space(1))) void*)(gB1 + k0),
                                     (__attribute__((address_space(3))) void*)((char*)Bs[buf] + ldsOff1), 16, 0, 0);
  };

  STAGE(0, 0);
  __syncthreads();               // drain prologue loads

  constexpr int NT = C_ / 32;    // 24 K-steps
#pragma unroll 2
  for (int t = 0; t < NT; ++t) {
    const int cur = t & 1;
    if (t + 1 < NT) STAGE(cur ^ 1, (t + 1) * 32);   // issue next-tile loads FIRST

    bf16x8 af[2], bfr[4];
#pragma unroll
    for (int mi = 0; mi < 2; mi++)
      af[mi] = *reinterpret_cast<const bf16x8*>(&As[cur][(wm * 32 + mi * 16 + l15) * 32 + quad * 8]);
#pragma unroll
    for (int ni = 0; ni < 4; ni++)
      bfr[ni] = *reinterpret_cast<const bf16x8*>(&Bs[cur][(wn * 64 + ni * 16 + l15) * 32 + quad * 8]);
    if (isqk) {
#pragma unroll
      for (int mi = 0; mi < 2; mi++)
#pragma unroll
        for (int ni = 0; ni < 4; ni++)
          acc[mi][ni] = __builtin_amdgcn_mfma_f32_16x16x32_bf16(bfr[ni], af[mi], acc[mi][ni], 0, 0, 0);
    } else {
#pragma unroll
      for (int mi = 0; mi < 2; mi++)
#pragma unroll
        for (int ni = 0; ni < 4; ni++)
          acc[mi][ni] = __builtin_amdgcn_mfma_f32_16x16x32_bf16(af[mi], bfr[ni], acc[mi][ni], 0, 0, 0);
    }
    __syncthreads();             // one barrier per K-step: drains next-tile loads too
  }

  if (isqk) {
    // acc[mi][ni] = C^T tile: rows n = col0+wn*64+ni*16+quad*4+r, col t = row0+wm*32+mi*16+l15
#pragma unroll
    for (int mi = 0; mi < 2; mi++) {
      int t = row0 + wm * 32 + mi * 16 + l15;
      int b = t >> 11, tt = t & 2047;
#pragma unroll
      for (int ni = 0; ni < 4; ni++) {
        int cN0 = col0 + wn * 64 + ni * 16 + quad * 4;
        int which = cN0 / 768;                 // 0=q, 1=k
        int rem = cN0 - which * 768;
        int h = rem >> 6, d0 = rem & 63;
        float4 bv = *reinterpret_cast<const float4*>(bias + cN0);
        float sc = which ? 1.0f : QSCALE;      // pre-scale q for shift-free exp2 softmax
        bf16x4 pack;
        pack[0] = f2bf((acc[mi][ni][0] + bv.x) * sc);
        pack[1] = f2bf((acc[mi][ni][1] + bv.y) * sc);
        pack[2] = f2bf((acc[mi][ni][2] + bv.z) * sc);
        pack[3] = f2bf((acc[mi][ni][3] + bv.w) * sc);
        bf16_t* dst = which ? kout : qout;
        *reinterpret_cast<bf16x4*>(dst + (((size_t)b * NH_ + h) * T_ + tt) * HS_ + d0) = pack;
      }
    }
  } else {
    // acc[mi][ni]: rows t = row0+wm*32+mi*16+quad*4+r, col cN = col0+wn*64+ni*16+l15 (v columns)
#pragma unroll
    for (int mi = 0; mi < 2; mi++) {
      int trow = row0 + wm * 32 + mi * 16 + quad * 4;
      int b = trow >> 11, tt = trow & 2047;       // tt % 4 == 0
      int kt = tt >> 6, nj = (tt >> 4) & 3, qd = (tt >> 2) & 3;
#pragma unroll
      for (int ni = 0; ni < 4; ni++) {
        int cN = col0 + wn * 64 + ni * 16 + l15;
        int rem = cN - 1536;
        int h = rem >> 6, d = rem & 63;
        int bh = b * NH_ + h;
        float bv = bias[cN];
        f16x4 pk;
#pragma unroll
        for (int r2 = 0; r2 < 4; r2++) pk[r2] = (_Float16)(acc[mi][ni][r2] + bv);
        // attn-fragment-direct layout (R28): f16 idx = bh*131072 + kt*4096 + ni*1024
        //   + p*512 + L*8 + e  with ni=nj, L=qd*16+(d&15), p=(d>>5)&1, e=((d>>4)&1)*4+r
        size_t off = (size_t)bh * 131072 + (size_t)kt * 4096 + (size_t)nj * 1024
                   + (size_t)((d >> 5) & 1) * 512 + (size_t)qd * 128
                   + (size_t)(d & 15) * 8 + (size_t)((d >> 4) & 1) * 4;
        *reinterpret_cast<f16x4*>(va + off) = pk;
      }
    }
  }
}

// ---------------- flash attention: R21 grid/K-staging + DIRECT-V (no V LDS) ----------------
// R28: V-staging dropped (Common-mistake #7 / m169 precedent: LDS-staging cache-resident
// attn operands is pure overhead). The GEMM now writes va in the attn-fragment-direct
// layout, so each (ni,p) wave read is 64 lanes x 16B = 1024B CONTIGUOUS from L2 (XCD-
// pinned working set) -- unlike R19's K gather (16-line/instr) which stays LDS-staged.
// V loads issue at tile top -> ~200cyc L2 latency hides under QK+softmax. Per thread per
// tile: -4 global loads, -4 LDS stores; SSTORE vmcnt covers 4 loads not 8; LDS 35->18KB.
// Values/MFMA order identical -> bitwise-identical output.
__global__ __launch_bounds__(128) void attn_kernel(const bf16_t* __restrict__ qb,
                                                   const bf16_t* __restrict__ kb,
                                                   const _Float16* __restrict__ va,
                                                   float* __restrict__ out) {
  __shared__ bf16_t Ks[2][64][72];          // 18432 B (V LDS removed)
  const int tid = threadIdx.x;              // 0..127
  const int lane = tid & 63, wave = tid >> 6;
  const int quad = lane >> 4, l15 = lane & 15;
  const int id = (int)blockIdx.x;           // 0..767
  const int xcd = id & 7, within = id >> 3; // 0..95; round-robin block->XCD assumption
  const int bh = xcd * 3 + within / 32;     // 3 bh per XCD -> L2-resident K/V/Q
  const int pairIdx = within & 31;          // 0..31
  const bf16_t* Qg = qb + (size_t)bh * T_ * HS_;
  const bf16_t* Kg = kb + (size_t)bh * T_ * HS_;
  const _Float16* Vg = va + (size_t)bh * 131072;            // per kt: 4096 f16

  // K staging geometry (per thread: 64B of K per k-tile)
  const int krow = tid >> 1, kcolB = (tid & 1) * 64;  // K: 64 rows x 128B, 2 threads/row

  int4 rk0, rk1, rk2, rk3;
  const char* kp;
  auto GLOAD = [&]() {                    // loads current kp, then advances one tile
    rk0 = *reinterpret_cast<const int4*>(kp);
    rk1 = *reinterpret_cast<const int4*>(kp + 16);
    rk2 = *reinterpret_cast<const int4*>(kp + 32);
    rk3 = *reinterpret_cast<const int4*>(kp + 48);
    kp += 8192;
  };
  auto SSTORE = [&](int buf) {
    char* kd = (char*)&Ks[buf][krow][0] + kcolB;
    *reinterpret_cast<int4*>(kd) = rk0;
    *reinterpret_cast<int4*>(kd + 16) = rk1;
    *reinterpret_cast<int4*>(kd + 32) = rk2;
    *reinterpret_cast<int4*>(kd + 48) = rk3;
  };

#pragma unroll
  for (int part = 0; part < 2; part++) {
    const int qtile = part ? pairIdx : 63 - pairIdx;   // 32-row q-tile index, 0..63
    const int qrow_base = qtile * 32 + wave * 16;
    const int qmax = qrow_base + 15;
    const int qcol = qrow_base + l15;        // this lane's q row
    const int nkt = (qtile >> 1) + 1;        // 64-wide k-tiles needed

    // Q B-fragments (pre-scaled by QSCALE in GEMM), held across the k loop
    bf16x8 bq0 = *reinterpret_cast<const bf16x8*>(Qg + (size_t)qcol * HS_ + quad * 8);
    bf16x8 bq1 = *reinterpret_cast<const bf16x8*>(Qg + (size_t)qcol * HS_ + 32 + quad * 8);

    float lsum = 0.f;
    f32x4 Oacc[4];
#pragma unroll
    for (int mi = 0; mi < 4; mi++) Oacc[mi] = f32x4{0.f, 0.f, 0.f, 0.f};

    kp = (const char*)Kg + krow * 128 + kcolB;
    GLOAD();
    __syncthreads();          // all waves done reading previous part's K buffers
    SSTORE(0);
    __syncthreads();

    for (int kt = 0; kt < nkt; kt++) {
      const int cur = kt & 1;
      const bool last = (kt + 1 >= nkt);
      if (!last) GLOAD();

      // direct-V fragment loads for THIS tile: issue early, consume after QK+softmax.
      // per (ni,p): 64 lanes x 16B = 1024B contiguous, L2-resident (XCD-pinned).
      const _Float16* Vt = Vg + (size_t)kt * 4096 + lane * 8;
      f16x8 vR[4][2];
#pragma unroll
      for (int ni = 0; ni < 4; ni++) {
        vR[ni][0] = *reinterpret_cast<const f16x8*>(Vt + ni * 1024);
        vR[ni][1] = *reinterpret_cast<const f16x8*>(Vt + ni * 1024 + 512);
      }

      const bool diag = (kt == nkt - 1);
      f16x4 pf[4];
#pragma unroll
      for (int ni = 0; ni < 4; ni++) {
        if (diag && (kt * 64 + ni * 16 > qmax)) continue;
        bf16x8 ka0 = *reinterpret_cast<const bf16x8*>(&Ks[cur][ni * 16 + l15][quad * 8]);
        bf16x8 ka1 = *reinterpret_cast<const bf16x8*>(&Ks[cur][ni * 16 + l15][32 + quad * 8]);
        f32x4 s = {0.f, 0.f, 0.f, 0.f};
        s = __builtin_amdgcn_mfma_f32_16x16x32_bf16(ka0, bq0, s, 0, 0, 0);
        s = __builtin_amdgcn_mfma_f32_16x16x32_bf16(ka1, bq1, s, 0, 0, 0);
        float p0 = __builtin_amdgcn_exp2f(s[0]);
        float p1 = __builtin_amdgcn_exp2f(s[1]);
        float p2 = __builtin_amdgcn_exp2f(s[2]);
        float p3 = __builtin_amdgcn_exp2f(s[3]);
        if (diag) {
          int jb = kt * 64 + ni * 16 + quad * 4;
          if (jb + 0 > qcol) p0 = 0.f;
          if (jb + 1 > qcol) p1 = 0.f;
          if (jb + 2 > qcol) p2 = 0.f;
          if (jb + 3 > qcol) p3 = 0.f;
        }
        lsum += (p0 + p1) + (p2 + p3);
        f16x2 lo2 = __builtin_bit_cast(f16x2, __builtin_amdgcn_cvt_pkrtz(p0, p1));
        f16x2 hi2 = __builtin_bit_cast(f16x2, __builtin_amdgcn_cvt_pkrtz(p2, p3));
        pf[ni] = f16x4{lo2[0], lo2[1], hi2[0], hi2[1]};
      }
      // O^T += V^T P^T (V from registers, loaded direct)
#pragma unroll
      for (int ni = 0; ni < 4; ni++) {
        if (diag && (kt * 64 + ni * 16 > qmax)) continue;
#pragma unroll
        for (int p = 0; p < 2; p++) {
          f16x8 vv = vR[ni][p];
          f16x4 lo = __builtin_shufflevector(vv, vv, 0, 1, 2, 3);
          f16x4 hi = __builtin_shufflevector(vv, vv, 4, 5, 6, 7);
          Oacc[2 * p]     = __builtin_amdgcn_mfma_f32_16x16x16f16(lo, pf[ni], Oacc[2 * p], 0, 0, 0);
          Oacc[2 * p + 1] = __builtin_amdgcn_mfma_f32_16x16x16f16(hi, pf[ni], Oacc[2 * p + 1], 0, 0, 0);
        }
      }

      if (!last) {
        SSTORE(1 - cur);      // vmcnt waits only the 4 K loads now
        __syncthreads();
      }
    }

    // lane-local lsum -> full row sum (reduce across the 4 quads)
    lsum += __shfl_xor(lsum, 16, 64);
    lsum += __shfl_xor(lsum, 32, 64);
    float rinv = 1.0f / lsum;

    // O^T tile -> out[bh][q][d], 16B stores
#pragma unroll
    for (int mi = 0; mi < 4; mi++) {
      float4 o;
      o.x = Oacc[mi][0] * rinv;
      o.y = Oacc[mi][1] * rinv;
      o.z = Oacc[mi][2] * rinv;
      o.w = Oacc[mi][3] * rinv;
      *reinterpret_cast<float4*>(out + ((size_t)bh * T_ + qcol) * HS_ + mi * 16 + quad * 4) = o;
    }
  }
}

extern "C" void kernel_launch(void* const* d_in, const int* in_sizes, int n_in,
                              void* d_out, int out_size, void* d_ws, size_t ws_size,
                              hipStream_t stream) {
  const float* x = (const float*)d_in[0];
  const float* w = (const float*)d_in[1];
  const float* bias = (const float*)d_in[2];
  float* out = (float*)d_out;

  char* ws = (char*)d_ws;
  bf16_t* xb = (bf16_t*)(ws);                            // 6,291,456 B
  bf16_t* wt = (bf16_t*)(ws + 6291456);                  // 3,538,944 B
  bf16_t* qb = (bf16_t*)(ws + 6291456 + 3538944);        // 6,291,456 B
  bf16_t* kb = qb + 3145728;                             // 6,291,456 B
  _Float16* va = (_Float16*)(kb + 3145728);              // 6,291,456 B

  cvt_xw_kernel<<<dim3(3072 + 1728), dim3(256), 0, stream>>>(x, w, xb, wt);
  gemm_qkv<<<dim3(1152), dim3(256), 0, stream>>>(xb, wt, bias, qb, kb, va);
  attn_kernel<<<dim3(768), dim3(128), 0, stream>>>(qb, kb, va, out);
}

// Round 16
// 140.316 us; speedup vs baseline: 1.0376x; 1.0376x over previous
//
#include <hip/hip_runtime.h>

typedef __bf16 bf16_t;
typedef __bf16 bf16x8 __attribute__((ext_vector_type(8)));
typedef __bf16 bf16x4 __attribute__((ext_vector_type(4)));
typedef _Float16 f16x2 __attribute__((ext_vector_type(2)));
typedef _Float16 f16x4 __attribute__((ext_vector_type(4)));
typedef _Float16 f16x8 __attribute__((ext_vector_type(8)));
typedef float f32x4 __attribute__((ext_vector_type(4)));

#define B_   2
#define T_   2048
#define C_   768
#define NH_  12
#define HS_  64
#define N3_  2304
#define M_   4096
#define QSCALE 0.18033688011112042f   // 0.125 * log2(e), folded into Q at GEMM epilogue

__device__ __forceinline__ bf16_t f2bf(float f) {
  unsigned u = __builtin_bit_cast(unsigned, f);
  u += 0x7fffu + ((u >> 16) & 1u);           // round-to-nearest-even
  unsigned short s = (unsigned short)(u >> 16);
  return __builtin_bit_cast(bf16_t, s);
}

// ---------------- fused casts: x fp32->bf16, w fp32 [K][N] -> wt bf16 [N][K] ----------------
// Exact R23 version (best-measured total 141.1us, reproduced twice).
__global__ __launch_bounds__(256) void cvt_xw_kernel(const float* __restrict__ x,
                                                     const float* __restrict__ w,
                                                     bf16_t* __restrict__ xb,
                                                     bf16_t* __restrict__ wt) {
  __shared__ float tile[32][33];
  int bx = blockIdx.x;
  if (bx < 3072) {
    int i = (bx * 256 + threadIdx.x) * 4;
    float4 v = *reinterpret_cast<const float4*>(x + i);
    xb[i + 0] = f2bf(v.x);
    xb[i + 1] = f2bf(v.y);
    xb[i + 2] = f2bf(v.z);
    xb[i + 3] = f2bf(v.w);
  } else {
    int b = bx - 3072;                 // 0..1727
    int k0 = (b % 24) * 32, n0 = (b / 24) * 32;
    int tx = threadIdx.x & 31, ty = threadIdx.x >> 5;   // 32 x 8
#pragma unroll
    for (int i = 0; i < 4; i++)
      tile[ty + i * 8][tx] = w[(size_t)(k0 + ty + i * 8) * N3_ + n0 + tx];
    __syncthreads();
#pragma unroll
    for (int i = 0; i < 4; i++)
      wt[(size_t)(n0 + ty + i * 8) * C_ + k0 + tx] = f2bf(tile[tx][ty + i * 8]);
  }
}

// ---------------- qkv GEMM: R15 pipeline + 2D-region XCD pinning (R23, best) ---------------
// R23: linear-grid L2 thrash (FETCH 42.4MB = 4.2x) fixed by region pinning: xcd = id&7 ->
// (xcd&1) col-half x (xcd>>1) row-quarter; per-XCD footprint 3.3MB < 4MB L2; 9 consecutive
// blocks share one A-panel. Output bitwise-identical to linear order.
// SESSION FINAL NOTE: T2/T4/T5 catalog-null on this 2-phase structure (R14/R22 confirmed);
// 8-phase 256^2 template geometrically infeasible (144 blocks = 0.56/CU). ~40us = floor.
__global__ __launch_bounds__(256) void gemm_qkv(const bf16_t* __restrict__ xb,
                                                const bf16_t* __restrict__ wt,
                                                const float* __restrict__ bias,
                                                bf16_t* __restrict__ qout,
                                                bf16_t* __restrict__ kout,
                                                _Float16* __restrict__ va) {
  __shared__ bf16_t As[2][64 * 32];    // [buf][m][k] panel, flat, no pad (64B rows)
  __shared__ bf16_t Bs[2][128 * 32];
  const int tid = threadIdx.x;
  const int lane = tid & 63, wave = tid >> 6;
  const int wm = wave >> 1, wn = wave & 1;   // 2(M) x 2(N) waves; wave tile 32x64
  const int quad = lane >> 4, l15 = lane & 15;

  // 2D-region XCD decode: 8 regions of 9 cols x 16 rows (144 blocks each)
  const int id = (int)blockIdx.x;           // 0..1151
  const int xcd = id & 7, r = id >> 3;      // r: 0..143
  const int cx = r % 9, ry = r / 9;         // col-fastest within region (A-panel reuse)
  const int bx = (xcd & 1) * 9 + cx;        // 0..17
  const int by = (xcd >> 1) * 16 + ry;      // 0..63
  const int row0 = by * 64;
  const int col0 = bx * 128;
  const bool isqk = (col0 < 1536);

  f32x4 acc[2][4];
#pragma unroll
  for (int mi = 0; mi < 2; mi++)
#pragma unroll
    for (int ni = 0; ni < 4; ni++) acc[mi][ni] = f32x4{0.f, 0.f, 0.f, 0.f};

  const int r0 = tid >> 2, q0 = tid & 3;
  const int r1 = (256 + tid) >> 2, q1 = (256 + tid) & 3;
  const bf16_t* gA0 = xb + (size_t)(row0 + r0) * C_ + q0 * 8;
  const bf16_t* gB0 = wt + (size_t)(col0 + r0) * C_ + q0 * 8;
  const bf16_t* gB1 = wt + (size_t)(col0 + r1) * C_ + q1 * 8;
  const int ldsOff0 = (wave * 64) * 16;          // chunk block c=0
  const int ldsOff1 = (256 + wave * 64) * 16;    // chunk block c=1

  auto STAGE = [&](int buf, int k0) {
    __builtin_amdgcn_global_load_lds((const __attribute__((address_space(1))) void*)(gA0 + k0),
                                     (__attribute__((address_space(3))) void*)((char*)As[buf] + ldsOff0), 16, 0, 0);
    __builtin_amdgcn_global_load_lds((const __attribute__((address_space(1))) void*)(gB0 + k0),
                                     (__attribute__((address_space(3))) void*)((char*)Bs[buf] + ldsOff0), 16, 0, 0);
    __builtin_amdgcn_global_load_lds((const __attribute__((address_space(1))) void*)(gB1 + k0),
                                     (__attribute__((address_space(3))) void*)((char*)Bs[buf] + ldsOff1), 16, 0, 0);
  };

  STAGE(0, 0);
  __syncthreads();               // drain prologue loads

  constexpr int NT = C_ / 32;    // 24 K-steps
#pragma unroll 2
  for (int t = 0; t < NT; ++t) {
    const int cur = t & 1;
    if (t + 1 < NT) STAGE(cur ^ 1, (t + 1) * 32);   // issue next-tile loads FIRST

    bf16x8 af[2], bfr[4];
#pragma unroll
    for (int mi = 0; mi < 2; mi++)
      af[mi] = *reinterpret_cast<const bf16x8*>(&As[cur][(wm * 32 + mi * 16 + l15) * 32 + quad * 8]);
#pragma unroll
    for (int ni = 0; ni < 4; ni++)
      bfr[ni] = *reinterpret_cast<const bf16x8*>(&Bs[cur][(wn * 64 + ni * 16 + l15) * 32 + quad * 8]);
    if (isqk) {
#pragma unroll
      for (int mi = 0; mi < 2; mi++)
#pragma unroll
        for (int ni = 0; ni < 4; ni++)
          acc[mi][ni] = __builtin_amdgcn_mfma_f32_16x16x32_bf16(bfr[ni], af[mi], acc[mi][ni], 0, 0, 0);
    } else {
#pragma unroll
      for (int mi = 0; mi < 2; mi++)
#pragma unroll
        for (int ni = 0; ni < 4; ni++)
          acc[mi][ni] = __builtin_amdgcn_mfma_f32_16x16x32_bf16(af[mi], bfr[ni], acc[mi][ni], 0, 0, 0);
    }
    __syncthreads();             // one barrier per K-step: drains next-tile loads too
  }

  if (isqk) {
    // acc[mi][ni] = C^T tile: rows n = col0+wn*64+ni*16+quad*4+r, col t = row0+wm*32+mi*16+l15
#pragma unroll
    for (int mi = 0; mi < 2; mi++) {
      int t = row0 + wm * 32 + mi * 16 + l15;
      int b = t >> 11, tt = t & 2047;
#pragma unroll
      for (int ni = 0; ni < 4; ni++) {
        int cN0 = col0 + wn * 64 + ni * 16 + quad * 4;
        int which = cN0 / 768;                 // 0=q, 1=k
        int rem = cN0 - which * 768;
        int h = rem >> 6, d0 = rem & 63;
        float4 bv = *reinterpret_cast<const float4*>(bias + cN0);
        float sc = which ? 1.0f : QSCALE;      // pre-scale q for shift-free exp2 softmax
        bf16x4 pack;
        pack[0] = f2bf((acc[mi][ni][0] + bv.x) * sc);
        pack[1] = f2bf((acc[mi][ni][1] + bv.y) * sc);
        pack[2] = f2bf((acc[mi][ni][2] + bv.z) * sc);
        pack[3] = f2bf((acc[mi][ni][3] + bv.w) * sc);
        bf16_t* dst = which ? kout : qout;
        *reinterpret_cast<bf16x4*>(dst + (((size_t)b * NH_ + h) * T_ + tt) * HS_ + d0) = pack;
      }
    }
  } else {
    // acc[mi][ni]: rows t = row0+wm*32+mi*16+quad*4+r, col cN = col0+wn*64+ni*16+l15 (v columns)
#pragma unroll
    for (int mi = 0; mi < 2; mi++) {
      int trow = row0 + wm * 32 + mi * 16 + quad * 4;
      int b = trow >> 11, tt = trow & 2047;       // tt % 4 == 0
      int kt = tt >> 6, nj = (tt >> 4) & 3, qd = (tt >> 2) & 3;
#pragma unroll
      for (int ni = 0; ni < 4; ni++) {
        int cN = col0 + wn * 64 + ni * 16 + l15;
        int rem = cN - 1536;
        int h = rem >> 6, d = rem & 63;
        int bh = b * NH_ + h;
        float bv = bias[cN];
        f16x4 pk;
#pragma unroll
        for (int r2 = 0; r2 < 4; r2++) pk[r2] = (_Float16)(acc[mi][ni][r2] + bv);
        size_t off = ((((((size_t)bh * 32 + kt) * 4 + nj) * 4 + qd) * 16 + (d & 15)) * 16) + (d >> 4) * 4;
        *reinterpret_cast<f16x4*>(va + off) = pk;
      }
    }
  }
}

// ---------------- flash attention: uniform 32-row blocks x XCD-pinned bh (R21, best) -------
// R21: uniform 768 2-wave blocks (pair (63-p,p) = 33 tiles each, 3 blocks/CU) with all 32
// pair-blocks of a bh on ONE XCD (3 bh/XCD = 2.25MB < 4MB L2).
// SESSION FINAL NOTE: per-tile chain (~1040cyc/slot vs ~400 issue) invariant across
// occupancy 6->17%, prefetch depth 1->2, barriers 2->1->0, L2-resident or not, V-staged
// or direct (R14/R17/R18/R19/R24/R26/R28 all null or regressed). Block-cost UNIFORMITY is
// the only grid lever under static round-robin placement. ~42us = this structure's floor;
// past it requires the co-designed 8-wave HK schedule (T16), not attempted here.
__global__ __launch_bounds__(128) void attn_kernel(const bf16_t* __restrict__ qb,
                                                   const bf16_t* __restrict__ kb,
                                                   const _Float16* __restrict__ va,
                                                   float* __restrict__ out) {
  __shared__ bf16_t Ks[2][64][72];          // 18432 B
  __shared__ _Float16 Vs[2][4][2][64][8];   // 16384 B  [buf][ni][p][lane][e]
  const int tid = threadIdx.x;              // 0..127
  const int lane = tid & 63, wave = tid >> 6;
  const int quad = lane >> 4, l15 = lane & 15;
  const int id = (int)blockIdx.x;           // 0..767
  const int xcd = id & 7, within = id >> 3; // 0..95; round-robin block->XCD assumption
  const int bh = xcd * 3 + within / 32;     // 3 bh per XCD -> L2-resident K/V/Q
  const int pairIdx = within & 31;          // 0..31
  const bf16_t* Qg = qb + (size_t)bh * T_ * HS_;
  const bf16_t* Kg = kb + (size_t)bh * T_ * HS_;
  const _Float16* Vg = va + (size_t)bh * 32 * 4096;         // per kt: 4096 f16

  // staging geometry (per thread: 64B of K, 64B of V per k-tile)
  const int krow = tid >> 1, kcolB = (tid & 1) * 64;  // K: 64 rows x 128B, 2 threads/row
  const int vni = tid >> 5, vlane = (tid & 31) * 2;   // V: units of 32B = [ni][lane][p0|p1]

  int4 rk0, rk1, rk2, rk3, rv0, rv1, rv2, rv3;
  const char* kp;
  const char* vp;
  auto GLOAD = [&]() {                    // loads current kp/vp, then advances one tile
    rk0 = *reinterpret_cast<const int4*>(kp);
    rk1 = *reinterpret_cast<const int4*>(kp + 16);
    rk2 = *reinterpret_cast<const int4*>(kp + 32);
    rk3 = *reinterpret_cast<const int4*>(kp + 48);
    rv0 = *reinterpret_cast<const int4*>(vp);
    rv1 = *reinterpret_cast<const int4*>(vp + 16);
    rv2 = *reinterpret_cast<const int4*>(vp + 32);
    rv3 = *reinterpret_cast<const int4*>(vp + 48);
    kp += 8192; vp += 8192;
  };
  auto SSTORE = [&](int buf) {
    char* kd = (char*)&Ks[buf][krow][0] + kcolB;
    *reinterpret_cast<int4*>(kd) = rk0;
    *reinterpret_cast<int4*>(kd + 16) = rk1;
    *reinterpret_cast<int4*>(kd + 32) = rk2;
    *reinterpret_cast<int4*>(kd + 48) = rk3;
    *reinterpret_cast<int4*>(&Vs[buf][vni][0][vlane][0]) = rv0;
    *reinterpret_cast<int4*>(&Vs[buf][vni][1][vlane][0]) = rv1;
    *reinterpret_cast<int4*>(&Vs[buf][vni][0][vlane + 1][0]) = rv2;
    *reinterpret_cast<int4*>(&Vs[buf][vni][1][vlane + 1][0]) = rv3;
  };

#pragma unroll
  for (int part = 0; part < 2; part++) {
    const int qtile = part ? pairIdx : 63 - pairIdx;   // 32-row q-tile index, 0..63
    const int qrow_base = qtile * 32 + wave * 16;
    const int qmax = qrow_base + 15;
    const int qcol = qrow_base + l15;        // this lane's q row
    const int nkt = (qtile >> 1) + 1;        // 64-wide k-tiles needed

    // Q B-fragments (pre-scaled by QSCALE in GEMM), held across the k loop
    bf16x8 bq0 = *reinterpret_cast<const bf16x8*>(Qg + (size_t)qcol * HS_ + quad * 8);
    bf16x8 bq1 = *reinterpret_cast<const bf16x8*>(Qg + (size_t)qcol * HS_ + 32 + quad * 8);

    float lsum = 0.f;
    f32x4 Oacc[4];
#pragma unroll
    for (int mi = 0; mi < 4; mi++) Oacc[mi] = f32x4{0.f, 0.f, 0.f, 0.f};

    kp = (const char*)Kg + krow * 128 + kcolB;
    vp = (const char*)Vg + tid * 64;
    GLOAD();
    __syncthreads();          // all waves done reading previous part's buffers
    SSTORE(0);
    __syncthreads();

    for (int kt = 0; kt < nkt; kt++) {
      const int cur = kt & 1;
      const bool last = (kt + 1 >= nkt);
      if (!last) GLOAD();

      const bool diag = (kt == nkt - 1);
      f16x4 pf[4];
#pragma unroll
      for (int ni = 0; ni < 4; ni++) {
        if (diag && (kt * 64 + ni * 16 > qmax)) continue;
        bf16x8 ka0 = *reinterpret_cast<const bf16x8*>(&Ks[cur][ni * 16 + l15][quad * 8]);
        bf16x8 ka1 = *reinterpret_cast<const bf16x8*>(&Ks[cur][ni * 16 + l15][32 + quad * 8]);
        f32x4 s = {0.f, 0.f, 0.f, 0.f};
        s = __builtin_amdgcn_mfma_f32_16x16x32_bf16(ka0, bq0, s, 0, 0, 0);
        s = __builtin_amdgcn_mfma_f32_16x16x32_bf16(ka1, bq1, s, 0, 0, 0);
        float p0 = __builtin_amdgcn_exp2f(s[0]);
        float p1 = __builtin_amdgcn_exp2f(s[1]);
        float p2 = __builtin_amdgcn_exp2f(s[2]);
        float p3 = __builtin_amdgcn_exp2f(s[3]);
        if (diag) {
          int jb = kt * 64 + ni * 16 + quad * 4;
          if (jb + 0 > qcol) p0 = 0.f;
          if (jb + 1 > qcol) p1 = 0.f;
          if (jb + 2 > qcol) p2 = 0.f;
          if (jb + 3 > qcol) p3 = 0.f;
        }
        lsum += (p0 + p1) + (p2 + p3);
        f16x2 lo2 = __builtin_bit_cast(f16x2, __builtin_amdgcn_cvt_pkrtz(p0, p1));
        f16x2 hi2 = __builtin_bit_cast(f16x2, __builtin_amdgcn_cvt_pkrtz(p2, p3));
        pf[ni] = f16x4{lo2[0], lo2[1], hi2[0], hi2[1]};
      }
      // O^T += V^T P^T
#pragma unroll
      for (int ni = 0; ni < 4; ni++) {
        if (diag && (kt * 64 + ni * 16 > qmax)) continue;
#pragma unroll
        for (int p = 0; p < 2; p++) {
          f16x8 vv = *reinterpret_cast<const f16x8*>(&Vs[cur][ni][p][lane][0]);
          f16x4 lo = __builtin_shufflevector(vv, vv, 0, 1, 2, 3);
          f16x4 hi = __builtin_shufflevector(vv, vv, 4, 5, 6, 7);
          Oacc[2 * p]     = __builtin_amdgcn_mfma_f32_16x16x16f16(lo, pf[ni], Oacc[2 * p], 0, 0, 0);
          Oacc[2 * p + 1] = __builtin_amdgcn_mfma_f32_16x16x16f16(hi, pf[ni], Oacc[2 * p + 1], 0, 0, 0);
        }
      }

      if (!last) {
        SSTORE(1 - cur);      // compiler waits vmcnt for rk/rv here (after compute)
        __syncthreads();
      }
    }

    // lane-local lsum -> full row sum (reduce across the 4 quads)
    lsum += __shfl_xor(lsum, 16, 64);
    lsum += __shfl_xor(lsum, 32, 64);
    float rinv = 1.0f / lsum;

    // O^T tile -> out[bh][q][d], 16B stores
#pragma unroll
    for (int mi = 0; mi < 4; mi++) {
      float4 o;
      o.x = Oacc[mi][0] * rinv;
      o.y = Oacc[mi][1] * rinv;
      o.z = Oacc[mi][2] * rinv;
      o.w = Oacc[mi][3] * rinv;
      *reinterpret_cast<float4*>(out + ((size_t)bh * T_ + qcol) * HS_ + mi * 16 + quad * 4) = o;
    }
  }
}

extern "C" void kernel_launch(void* const* d_in, const int* in_sizes, int n_in,
                              void* d_out, int out_size, void* d_ws, size_t ws_size,
                              hipStream_t stream) {
  const float* x = (const float*)d_in[0];
  const float* w = (const float*)d_in[1];
  const float* bias = (const float*)d_in[2];
  float* out = (float*)d_out;

  char* ws = (char*)d_ws;
  bf16_t* xb = (bf16_t*)(ws);                            // 6,291,456 B
  bf16_t* wt = (bf16_t*)(ws + 6291456);                  // 3,538,944 B
  bf16_t* qb = (bf16_t*)(ws + 6291456 + 3538944);        // 6,291,456 B
  bf16_t* kb = qb + 3145728;                             // 6,291,456 B
  _Float16* va = (_Float16*)(kb + 3145728);              // 6,291,456 B

  cvt_xw_kernel<<<dim3(3072 + 1728), dim3(256), 0, stream>>>(x, w, xb, wt);
  gemm_qkv<<<dim3(1152), dim3(256), 0, stream>>>(xb, wt, bias, qb, kb, va);
  attn_kernel<<<dim3(768), dim3(128), 0, stream>>>(qb, kb, va, out);
}